// Round 4
// baseline (29047.302 us; speedup 1.0000x reference)
//
#include <hip/hip_runtime.h>

#define T_STEPS 65536
#define NIN 99
#define HID 64
#define G4 256   // 4*HID gates
#define TS 128   // timesteps per block in the projection kernel
#define PF 4     // prefetch depth (steps) in the recurrence kernel

typedef _Float16 half2v __attribute__((ext_vector_type(2)));

__device__ __forceinline__ float frcp(float x) { return __builtin_amdgcn_rcpf(x); }
__device__ __forceinline__ float fexp2(float x) { return __builtin_amdgcn_exp2f(x); }

#define LOG2E 1.4426950408889634f

__device__ __forceinline__ float sigmoid_f(float x) { return frcp(1.0f + fexp2(x * -LOG2E)); }
__device__ __forceinline__ float tanh_f(float x) {
    float ax = fabsf(x);
    float e  = fexp2(ax * (2.0f * LOG2E));     // inf for large ax fine: rcp(inf)=0
    float r  = 1.0f - 2.0f * frcp(e + 1.0f);
    return copysignf(r, x);
}

// pack two f32 into half2 (v_cvt_pkrtz_f16_f32, 1 instr); bit-cast from the
// builtin's __fp16-vector return type to the _Float16-vector fdot2 wants.
__device__ __forceinline__ half2v pk16(float a, float b) {
#if __has_builtin(__builtin_amdgcn_cvt_pkrtz)
    return __builtin_bit_cast(half2v, __builtin_amdgcn_cvt_pkrtz(a, b));
#else
    half2v r; r.x = (_Float16)a; r.y = (_Float16)b; return r;
#endif
}
// v_dot2_f32_f16: 2 MACs per instr, f32 accumulate. Fallback keeps it compiling.
__device__ __forceinline__ float fdot2f(half2v a, half2v b, float c) {
#if __has_builtin(__builtin_amdgcn_fdot2)
    return __builtin_amdgcn_fdot2(a, b, c, false);
#else
    return fmaf((float)a.x, (float)b.x, fmaf((float)a.y, (float)b.y, c));
#endif
}

// ---------------- Kernel 1: xz2[t][unit][4] = gates (i,f,g,o) of unit ----------------
__global__ __launch_bounds__(256, 1) void xz_kernel(
    const float* __restrict__ x, const float* __restrict__ W_ih,
    const float* __restrict__ b_ih, const float* __restrict__ b_hh,
    float* __restrict__ xz2) {
    __shared__ __align__(16) float xs[TS * 100];   // padded rows: 400 B stride
    const int g  = threadIdx.x;                    // gate row 0..255
    const int t0 = blockIdx.x * TS;
    const int unit = g & 63, d = g >> 6;           // transposed write position

    for (int i = g; i < TS * NIN; i += 256) {
        int tl = i / NIN;
        int j  = i - tl * NIN;
        xs[tl * 100 + j] = x[(size_t)t0 * NIN + i];
    }

    float w[NIN];
#pragma unroll
    for (int j = 0; j < NIN; ++j) w[j] = W_ih[g * NIN + j];
    const float bias = b_ih[g] + b_hh[g];
    __syncthreads();

    for (int tl = 0; tl < TS; ++tl) {
        const float* xr = &xs[tl * 100];
        float a0 = bias, a1 = 0.f, a2 = 0.f, a3 = 0.f;
#pragma unroll
        for (int j4 = 0; j4 < 24; ++j4) {
            float4 xv = *(const float4*)(xr + 4 * j4);
            a0 = fmaf(w[4 * j4 + 0], xv.x, a0);
            a1 = fmaf(w[4 * j4 + 1], xv.y, a1);
            a2 = fmaf(w[4 * j4 + 2], xv.z, a2);
            a3 = fmaf(w[4 * j4 + 3], xv.w, a3);
        }
        a0 = fmaf(w[96], xr[96], a0);
        a1 = fmaf(w[97], xr[97], a1);
        a2 = fmaf(w[98], xr[98], a2);
        xz2[(size_t)(t0 + tl) * G4 + unit * 4 + d] = (a0 + a1) + (a2 + a3);
    }
}

// ---------------- Kernel 2: SINGLE-WAVE LSTM — no barriers, no LDS in step loop ----------
// R3 post-mortem: 855 cy/step measured vs ~180 cy issue -> the 4-wave split-K
// exchange (ds_write + lgkmcnt + s_barrier + ds_read, every step) was ~650 cy
// of pure latency. One wave, lane l = unit l, all 4 gates over full K=64:
//   per step: 1 mov_dpp + 1 cvt_pkrtz + 32 readlane (packed h pairs)
//             + 128 v_dot2_f32_f16 (2 accums/gate -> 8 independent chains)
//             + activations. ~200 instr * 2cy + tail ~ 460 cy/step.
// Weights: 4 gates * 32 packed half2 = 128 VGPRs (fine at 1 wave/SIMD).
__global__ __launch_bounds__(64, 1) __attribute__((amdgpu_waves_per_eu(1)))
void lstm_kernel(
    const float* __restrict__ xz2, const float* __restrict__ W_hh,
    const float* __restrict__ W1, const float* __restrict__ W2,
    const float* __restrict__ b2, float* __restrict__ out) {
    __shared__ float hfin[HID];
    __shared__ float hbuf[32];
    const int l = threadIdx.x;     // 0..63, unit index

    // W_hh rows l (i), 64+l (f), 128+l (g), 192+l (o); full K=64 per gate,
    // packed once into 32 half2 per gate (f32 -> f16 RTZ)
    const float* Wb = W_hh + l * HID;
    int wiP[32], wfP[32], wgP[32], woP[32];
#pragma unroll
    for (int j = 0; j < 32; ++j) {
        wiP[j] = __builtin_bit_cast(int, pk16(Wb[2 * j + 0],     Wb[2 * j + 1]));
        wfP[j] = __builtin_bit_cast(int, pk16(Wb[2 * j + 4096],  Wb[2 * j + 4097]));
        wgP[j] = __builtin_bit_cast(int, pk16(Wb[2 * j + 8192],  Wb[2 * j + 8193]));
        woP[j] = __builtin_bit_cast(int, pk16(Wb[2 * j + 12288], Wb[2 * j + 12289]));
        asm volatile("" : "+v"(wiP[j]), "+v"(wfP[j]), "+v"(wgP[j]), "+v"(woP[j]));
    }

    float h = 0.0f, c = 0.0f;      // lane l: h[l], c[l]

    // xz columns: unit l's 4 gates contiguous -> one dwordx4 per step; wave
    // reads one contiguous 1KB row per step. PF=4 block prefetch covers
    // ~4*500cy > HBM miss latency.
    const float* zi = xz2 + 4 * l;
    float4 zcur[PF], znxt[PF];
#pragma unroll
    for (int p = 0; p < PF; ++p) zcur[p] = *(const float4*)(zi + (size_t)p * G4);

    for (int tb = 0; tb < T_STEPS; tb += PF) {
        if (tb + PF < T_STEPS) {
#pragma unroll
            for (int p = 0; p < PF; ++p)
                znxt[p] = *(const float4*)(zi + (size_t)(tb + PF + p) * G4);
        }
#pragma unroll
        for (int u = 0; u < PF; ++u) {
            const float4 z = zcur[u];
            float ai0 = z.x, af0 = z.y, ag0 = z.z, ao0 = z.w;
            float ai1 = 0.f, af1 = 0.f, ag1 = 0.f, ao1 = 0.f;

            // pack (h[2j], h[2j+1]) in even lanes: lane-xor-1 neighbor via DPP
#if __has_builtin(__builtin_amdgcn_mov_dpp)
            float hn = __int_as_float(__builtin_amdgcn_mov_dpp(
                __float_as_int(h), 0xB1 /*quad_perm [1,0,3,2]*/, 0xF, 0xF, true));
#else
            float hn = __shfl_xor(h, 1, 64);
#endif
            const int hpi = __builtin_bit_cast(int, pk16(h, hn));
#pragma unroll
            for (int j = 0; j < 16; ++j) {
                half2v hp0 = __builtin_bit_cast(half2v,
                    __builtin_amdgcn_readlane(hpi, 4 * j + 0));   // (h4j,   h4j+1)
                half2v hp1 = __builtin_bit_cast(half2v,
                    __builtin_amdgcn_readlane(hpi, 4 * j + 2));   // (h4j+2, h4j+3)
                ai0 = fdot2f(__builtin_bit_cast(half2v, wiP[2 * j]),     hp0, ai0);
                af0 = fdot2f(__builtin_bit_cast(half2v, wfP[2 * j]),     hp0, af0);
                ag0 = fdot2f(__builtin_bit_cast(half2v, wgP[2 * j]),     hp0, ag0);
                ao0 = fdot2f(__builtin_bit_cast(half2v, woP[2 * j]),     hp0, ao0);
                ai1 = fdot2f(__builtin_bit_cast(half2v, wiP[2 * j + 1]), hp1, ai1);
                af1 = fdot2f(__builtin_bit_cast(half2v, wfP[2 * j + 1]), hp1, af1);
                ag1 = fdot2f(__builtin_bit_cast(half2v, wgP[2 * j + 1]), hp1, ag1);
                ao1 = fdot2f(__builtin_bit_cast(half2v, woP[2 * j + 1]), hp1, ao1);
            }
            float si = ai0 + ai1;
            float sf = af0 + af1;
            float sg = ag0 + ag1;
            float so = ao0 + ao1;
            float ig = sigmoid_f(si);
            float fg = sigmoid_f(sf);
            float gg = tanh_f(sg);
            float og = sigmoid_f(so);
            c = fmaf(fg, c, ig * gg);
            h = og * tanh_f(c);
        }
#pragma unroll
        for (int p = 0; p < PF; ++p) zcur[p] = znxt[p];
    }

    // head: out = W2 @ relu(W1 @ relu(h_T)) + b2  (single wave; syncthreads trivial)
    hfin[l] = h;
    __syncthreads();
    if (l < 32) {
        float s = 0.0f;
#pragma unroll
        for (int j = 0; j < HID; ++j) s += W1[l * HID + j] * fmaxf(hfin[j], 0.0f);
        hbuf[l] = fmaxf(s, 0.0f);
    }
    __syncthreads();
    if (l < 3) {
        float s = b2[l];
#pragma unroll
        for (int j = 0; j < 32; ++j) s += W2[l * 32 + j] * hbuf[j];
        out[l] = s;
    }
}

extern "C" void kernel_launch(void* const* d_in, const int* in_sizes, int n_in,
                              void* d_out, int out_size, void* d_ws, size_t ws_size,
                              hipStream_t stream) {
    const float* x   = (const float*)d_in[0];
    const float* Wih = (const float*)d_in[1];
    const float* Whh = (const float*)d_in[2];
    const float* bih = (const float*)d_in[3];
    const float* bhh = (const float*)d_in[4];
    const float* W1  = (const float*)d_in[5];
    const float* W2  = (const float*)d_in[6];
    const float* b2  = (const float*)d_in[7];
    float* out = (float*)d_out;
    float* xz2 = (float*)d_ws;   // T_STEPS * 256 floats = 64 MB (transposed layout)

    xz_kernel<<<T_STEPS / TS, 256, 0, stream>>>(x, Wih, bih, bhh, xz2);
    lstm_kernel<<<1, 64, 0, stream>>>(xz2, Whh, W1, W2, b2, out);
}